// Round 1
// baseline (509.863 us; speedup 1.0000x reference)
//
#include <hip/hip_runtime.h>
#include <stdint.h>

// Problem constants
#define QP 127.0f
#define HW2 50176            // 224*224
#define NPIX 1605632         // 32*224*224
#define NELEM 25690112       // 32*16*224*224

// ws layout (bytes)
#define WS_WQ   256          // 576 dwords packed weights
#define WS_PART 4096         // 1568*32 floats of per-block stat partials
#define WS_XQ   (1 << 20)    // NPIX * 16B of cin-packed int8 activations

__device__ __forceinline__ int dot4(int a, int b, int c) {
#if defined(__has_builtin) && __has_builtin(__builtin_amdgcn_sdot4)
  return __builtin_amdgcn_sdot4(a, b, c, false);
#else
  int r = c;
  r += (int)(signed char)(a)       * (int)(signed char)(b);
  r += (int)(signed char)(a >> 8)  * (int)(signed char)(b >> 8);
  r += (int)(signed char)(a >> 16) * (int)(signed char)(b >> 16);
  r += (a >> 24) * (b >> 24);
  return r;
#endif
}

// ---------------- K1: absmax(x) ----------------
__global__ void k_absmax(const float* __restrict__ x, unsigned* __restrict__ absmax_bits) {
  const float4* x4 = (const float4*)x;
  const int n4 = NELEM / 4;
  float m = 0.0f;
  for (int i = blockIdx.x * blockDim.x + threadIdx.x; i < n4; i += gridDim.x * blockDim.x) {
    float4 v = x4[i];
    m = fmaxf(m, fmaxf(fmaxf(fabsf(v.x), fabsf(v.y)), fmaxf(fabsf(v.z), fabsf(v.w))));
  }
  #pragma unroll
  for (int off = 32; off; off >>= 1) m = fmaxf(m, __shfl_down(m, off, 64));
  __shared__ float red[4];
  int lane = threadIdx.x & 63, wv = threadIdx.x >> 6;
  if (lane == 0) red[wv] = m;
  __syncthreads();
  if (threadIdx.x == 0) {
    m = fmaxf(fmaxf(red[0], red[1]), fmaxf(red[2], red[3]));
    atomicMax(absmax_bits, __float_as_uint(m));  // all values >= 0: uint order == float order
  }
}

// ---------------- K2: quantize weights, compute scales ----------------
__global__ void k_quant_w(const float* __restrict__ w, char* __restrict__ ws) {
  unsigned* hdr_u = (unsigned*)ws;
  float* hdr_f = (float*)ws;
  int* wq = (int*)(ws + WS_WQ);
  float m = 0.0f;
  for (int i = threadIdx.x; i < 2304; i += 256) m = fmaxf(m, fabsf(w[i]));
  #pragma unroll
  for (int off = 32; off; off >>= 1) m = fmaxf(m, __shfl_down(m, off, 64));
  __shared__ float red[4];
  __shared__ float s_sw;
  if ((threadIdx.x & 63) == 0) red[threadIdx.x >> 6] = m;
  __syncthreads();
  if (threadIdx.x == 0) {
    float mw = fmaxf(fmaxf(red[0], red[1]), fmaxf(red[2], red[3]));
    float sw = mw / QP;                              // matches ref: step = alpha/qp (f32 div)
    float sx = __uint_as_float(hdr_u[0]) / QP;
    hdr_f[1] = sw;
    hdr_f[2] = sx * sw;                              // combined dequant scale
    s_sw = sw;
  }
  __syncthreads();
  float sw = s_sw;
  // pack: wq[(cout*9 + kh*3+kw)*4 + c4], byte j of dword = cin 4*c4+j
  for (int i = threadIdx.x; i < 576; i += 256) {
    int cout = i / 36; int r = i - cout * 36;
    int tap = r >> 2;  int c4 = r & 3;
    int kh = tap / 3, kw = tap - kh * 3;
    unsigned bits = 0;
    #pragma unroll
    for (int j = 0; j < 4; ++j) {
      int cin = c4 * 4 + j;
      float v = w[((cout * 16 + cin) * 3 + kh) * 3 + kw];
      int q = (int)rintf(v / sw);                    // rint = round-half-even = jnp.round
      q = max(-127, min(127, q));
      bits |= ((unsigned)(q & 0xff)) << (8 * j);
    }
    wq[i] = (int)bits;
  }
}

// ---------------- K3: quantize x -> NHWC cin-packed int8 ----------------
__global__ void k_quant_x(const float* __restrict__ x, char* __restrict__ ws) {
  const unsigned* hdr_u = (const unsigned*)ws;
  int4* xq = (int4*)(ws + WS_XQ);
  float sx = __uint_as_float(hdr_u[0]) / QP;
  int p = blockIdx.x * 256 + threadIdx.x;            // 6272*256 == NPIX exactly
  int n = p / HW2;
  int hw = p - n * HW2;
  const float* xb = x + (size_t)n * 16 * HW2 + hw;   // coalesced per-channel reads
  int q[16];
  #pragma unroll
  for (int c = 0; c < 16; ++c) {
    float t = xb[c * HW2] / sx;                      // f32 div, matches ref
    int qq = (int)rintf(t);
    q[c] = max(-127, min(127, qq));
  }
  int4 v;
  v.x = (int)(((unsigned)(q[0] & 0xff)) | ((unsigned)(q[1] & 0xff) << 8) | ((unsigned)(q[2] & 0xff) << 16) | ((unsigned)(q[3] & 0xff) << 24));
  v.y = (int)(((unsigned)(q[4] & 0xff)) | ((unsigned)(q[5] & 0xff) << 8) | ((unsigned)(q[6] & 0xff) << 16) | ((unsigned)(q[7] & 0xff) << 24));
  v.z = (int)(((unsigned)(q[8] & 0xff)) | ((unsigned)(q[9] & 0xff) << 8) | ((unsigned)(q[10] & 0xff) << 16) | ((unsigned)(q[11] & 0xff) << 24));
  v.w = (int)(((unsigned)(q[12] & 0xff)) | ((unsigned)(q[13] & 0xff) << 8) | ((unsigned)(q[14] & 0xff) << 16) | ((unsigned)(q[15] & 0xff) << 24));
  xq[p] = v;
}

// ---------------- K4/K6: int8 conv (stats pass / output pass) ----------------
// grid 1568 = 32 n * 7*7 tiles of 32x32 output pixels; 256 thr; 4 px x 16 cout per thread
template <bool WRITE_OUT>
__global__ __launch_bounds__(256) void k_conv(const char* __restrict__ ws,
                                              float* __restrict__ out,
                                              float* __restrict__ partials) {
  const int4* __restrict__ xq = (const int4*)(ws + WS_XQ);
  const int4* __restrict__ wq4 = (const int4*)(ws + WS_WQ);
  __shared__ int4 sX[34 * 34];
  __shared__ int4 sW[144];
  __shared__ float sRedS[4][16];
  __shared__ float sRedQ[4][16];

  int tid = threadIdx.x;
  int b = blockIdx.x;
  int n = b / 49; int r = b - n * 49;
  int t_y = r / 7, t_x = r - t_y * 7;
  int h0 = t_y * 32, w0 = t_x * 32;

  if (tid < 144) sW[tid] = wq4[tid];
  for (int i = tid; i < 34 * 34; i += 256) {
    int row = i / 34, col = i - row * 34;
    int gh = h0 - 1 + row, gw = w0 - 1 + col;
    int4 v = {0, 0, 0, 0};
    if ((unsigned)gh < 224u && (unsigned)gw < 224u)
      v = xq[(n * 224 + gh) * 224 + gw];
    sX[i] = v;
  }
  __syncthreads();

  int tx = tid & 31, ty = tid >> 5;
  int acc[4][16];
  #pragma unroll
  for (int p = 0; p < 4; ++p)
    #pragma unroll
    for (int c = 0; c < 16; ++c) acc[p][c] = 0;

  #pragma unroll
  for (int kh = 0; kh < 3; ++kh) {
    #pragma unroll
    for (int kw = 0; kw < 3; ++kw) {
      int4 xv[4];
      #pragma unroll
      for (int p = 0; p < 4; ++p) xv[p] = sX[(ty + 8 * p + kh) * 34 + tx + kw];
      #pragma unroll
      for (int c = 0; c < 16; ++c) {
        int4 wv = sW[c * 9 + kh * 3 + kw];
        #pragma unroll
        for (int p = 0; p < 4; ++p) {
          int a = acc[p][c];
          a = dot4(xv[p].x, wv.x, a);
          a = dot4(xv[p].y, wv.y, a);
          a = dot4(xv[p].z, wv.z, a);
          a = dot4(xv[p].w, wv.w, a);
          acc[p][c] = a;
        }
      }
    }
  }

  if (WRITE_OUT) {
    const float* hdr_f = (const float*)ws;
    #pragma unroll
    for (int c = 0; c < 16; ++c) {
      float A = hdr_f[16 + c], B = hdr_f[32 + c];
      #pragma unroll
      for (int p = 0; p < 4; ++p) {
        float y = fmaf((float)acc[p][c], A, B);
        y = fminf(fmaxf(y, 0.0f), 6.0f);
        out[((n * 16 + c) * 224 + (h0 + ty + 8 * p)) * 224 + (w0 + tx)] = y;
      }
    }
  } else {
    #pragma unroll
    for (int c = 0; c < 16; ++c) {
      int si = acc[0][c] + acc[1][c] + acc[2][c] + acc[3][c];  // exact in int32
      float ps = (float)si;
      float f0 = (float)acc[0][c], f1 = (float)acc[1][c];
      float f2 = (float)acc[2][c], f3 = (float)acc[3][c];
      float pq = f0 * f0 + f1 * f1 + f2 * f2 + f3 * f3;
      #pragma unroll
      for (int off = 32; off; off >>= 1) {
        ps += __shfl_down(ps, off, 64);
        pq += __shfl_down(pq, off, 64);
      }
      if ((tid & 63) == 0) { sRedS[tid >> 6][c] = ps; sRedQ[tid >> 6][c] = pq; }
    }
    __syncthreads();
    if (tid < 32) {
      int c = tid & 15;
      float t;
      if (tid < 16) t = sRedS[0][c] + sRedS[1][c] + sRedS[2][c] + sRedS[3][c];
      else          t = sRedQ[0][c] + sRedQ[1][c] + sRedQ[2][c] + sRedQ[3][c];
      partials[b * 32 + tid] = t;
    }
  }
}

// ---------------- K5: finalize BN coefficients ----------------
__global__ void k_finalize(const float* __restrict__ partials,
                           const float* __restrict__ gamma,
                           const float* __restrict__ beta,
                           float* __restrict__ hdr_f) {
  __shared__ double sd[256];
  int tid = threadIdx.x;
  int v = tid & 31;
  int g = tid >> 5;  // 8 groups
  double acc = 0.0;
  for (int i = g; i < 1568; i += 8) acc += (double)partials[i * 32 + v];
  sd[tid] = acc;
  __syncthreads();
  if (tid < 32) {
    double t = 0.0;
    #pragma unroll
    for (int g2 = 0; g2 < 8; ++g2) t += sd[g2 * 32 + tid];
    sd[tid] = t;
  }
  __syncthreads();
  if (tid < 16) {
    double s = (double)hdr_f[2];
    const double M = (double)NPIX;
    double mean = s * sd[tid] / M;
    double ey2 = s * s * sd[16 + tid] / M;
    double var = ey2 - mean * mean;                 // biased var, matches jnp.var
    double inv = (double)gamma[tid] / sqrt(var + 1e-5);
    hdr_f[16 + tid] = (float)(s * inv);             // A: applied to raw int accumulator
    hdr_f[32 + tid] = (float)((double)beta[tid] - mean * inv);  // B
  }
}

extern "C" void kernel_launch(void* const* d_in, const int* in_sizes, int n_in,
                              void* d_out, int out_size, void* d_ws, size_t ws_size,
                              hipStream_t stream) {
  const float* x = (const float*)d_in[0];
  const float* w = (const float*)d_in[1];
  const float* gamma = (const float*)d_in[2];
  const float* beta = (const float*)d_in[3];
  float* out = (float*)d_out;
  char* ws = (char*)d_ws;

  hipMemsetAsync(ws, 0, 256, stream);  // zero header (absmax accumulator)
  k_absmax<<<2048, 256, 0, stream>>>(x, (unsigned*)ws);
  k_quant_w<<<1, 256, 0, stream>>>(w, ws);
  k_quant_x<<<6272, 256, 0, stream>>>(x, ws);
  k_conv<false><<<1568, 256, 0, stream>>>(ws, nullptr, (float*)(ws + WS_PART));
  k_finalize<<<1, 256, 0, stream>>>((const float*)(ws + WS_PART), gamma, beta, (float*)ws);
  k_conv<true><<<1568, 256, 0, stream>>>(ws, out, nullptr);
}